// Round 5
// baseline (423.834 us; speedup 1.0000x reference)
//
#include <hip/hip_runtime.h>
#include <hip/hip_fp16.h>
#include <math.h>

constexpr int D = 128;
constexpr int CAPS = 2048;   // LDS coef slots per 64-node agg block (8KB)

struct __align__(16) H8 { __half2 h[4]; };

typedef _Float16     half8   __attribute__((ext_vector_type(8)));
typedef float        floatx4 __attribute__((ext_vector_type(4)));
typedef unsigned int uint4v  __attribute__((ext_vector_type(4)));
typedef unsigned int uint2v  __attribute__((ext_vector_type(2)));

// ---------------- preprocessing ----------------

__device__ __forceinline__ int detect64(const int* __restrict__ ei) {
  int z = 0;
#pragma unroll
  for (int i = 0; i < 8; ++i) z |= ei[2 * i + 1];
  return (z == 0) ? 1 : 0;
}

__device__ __forceinline__ void load_edge(const int* __restrict__ ei, int e, int nE,
                                          int m64, int n, int& r, int& c) {
  if (m64) { r = ei[2 * (size_t)e]; c = ei[2 * ((size_t)nE + e)]; }
  else     { r = ei[(size_t)e];     c = ei[(size_t)nE + e]; }
  r = min(max(r, 0), n - 1);
  c = min(max(c, 0), n - 1);
}

// cntdeg SPREAD: node i at cntdeg[i<<3] (one 64B line per node).
// blocks 0..23: transpose W1/W2/W3 -> Wt fp16 [n][k]; blocks 24..: zero cntdeg.
__global__ void k_setup(const float* __restrict__ W1, const float* __restrict__ W2,
                        const float* __restrict__ W3, __half* __restrict__ Wt,
                        unsigned long long* __restrict__ cntdeg, int n8) {
  int b = blockIdx.x;
  if (b < 24) {
    int m = b >> 3, s = b & 7;
    const float* W = m == 0 ? W1 : (m == 1 ? W2 : W3);
    __half* o = Wt + (size_t)m * D * D;
    int t = threadIdx.x;
    int nn = t & 127;
    int kh = t >> 7;
    int k0 = s * 16 + kh * 8;
    H8 hv;
#pragma unroll
    for (int jj = 0; jj < 4; ++jj) {
      float f0 = W[(size_t)(k0 + 2 * jj)     * D + nn];
      float f1 = W[(size_t)(k0 + 2 * jj + 1) * D + nn];
      hv.h[jj] = __floats2half2_rn(f0, f1);
    }
    *(H8*)(o + (size_t)nn * D + k0) = hv;
  } else {
    int i = (b - 24) * 256 + threadIdx.x;
    if (i < n8) cntdeg[i] = 0ULL;
  }
}

// ---------------- activations ----------------
template <int ACT>
__device__ __forceinline__ float act_f(float x) {
  if (ACT == 1) return x > 0.f ? x : expm1f(x);
  if (ACT == 2) return 0.5f * x * (1.0f + erff(x * 0.70710678118654752440f));
  return x;
}

// ---------------- MFMA GEMM body (fp32 A): Y = half(A @ W) ------------------
__device__ __forceinline__ void gemm_body(int bid, const float* __restrict__ A,
                                          const __half* __restrict__ Wt,
                                          __half* __restrict__ Y, int n) {
  const int wave = threadIdx.x >> 6;
  const int lane = threadIdx.x & 63;
  const int np = lane & 15;
  const int quad = lane >> 4;
  const int node = bid * 64 + wave * 16 + np;
  const int nc = min(node, n - 1);

  half8 b[4];
#pragma unroll
  for (int s = 0; s < 4; ++s) {
    const float* ap = A + (size_t)nc * D + s * 32 + quad * 8;
    floatx4 v0 = __builtin_nontemporal_load((const floatx4*)ap);
    floatx4 v1 = __builtin_nontemporal_load((const floatx4*)(ap + 4));
#pragma unroll
    for (int t = 0; t < 4; ++t) {
      b[s][t]     = (_Float16)v0[t];
      b[s][t + 4] = (_Float16)v1[t];
    }
  }

  floatx4 acc[8];
#pragma unroll
  for (int mt = 0; mt < 8; ++mt) acc[mt] = (floatx4){0.f, 0.f, 0.f, 0.f};

#pragma unroll
  for (int mt = 0; mt < 8; ++mt) {
#pragma unroll
    for (int s = 0; s < 4; ++s) {
      half8 a = *(const half8*)(Wt + (size_t)(mt * 16 + np) * D + s * 32 + quad * 8);
      acc[mt] = __builtin_amdgcn_mfma_f32_16x16x32_f16(a, b[s], acc[mt], 0, 0, 0);
    }
  }

  if (node < n) {
#pragma unroll
    for (int mt = 0; mt < 8; ++mt) {
      __half2 ha = __floats2half2_rn(acc[mt][0], acc[mt][1]);
      __half2 hb = __floats2half2_rn(acc[mt][2], acc[mt][3]);
      uint2v pv;
      pv[0] = *(unsigned int*)&ha;
      pv[1] = *(unsigned int*)&hb;
      int f0 = mt * 16 + quad * 4;
      __builtin_nontemporal_store(
          pv, (uint2v*)(Y + ((size_t)(f0 >> 5) * n + node) * 32 + (f0 & 31)));
    }
  }
}

// half-input (chunk layout, already activated) GEMM: Y = half(A @ W)
__global__ __launch_bounds__(256) void k_gemmh(const __half* __restrict__ A,
                                               const __half* __restrict__ Wt,
                                               __half* __restrict__ Y, int n) {
  const int wave = threadIdx.x >> 6;
  const int lane = threadIdx.x & 63;
  const int np = lane & 15;
  const int quad = lane >> 4;
  const int node = blockIdx.x * 64 + wave * 16 + np;
  const int nc = min(node, n - 1);

  half8 b[4];
#pragma unroll
  for (int s = 0; s < 4; ++s)
    b[s] = __builtin_nontemporal_load(
        (const half8*)(A + ((size_t)s * n + nc) * 32 + quad * 8));

  floatx4 acc[8];
#pragma unroll
  for (int mt = 0; mt < 8; ++mt) acc[mt] = (floatx4){0.f, 0.f, 0.f, 0.f};

#pragma unroll
  for (int mt = 0; mt < 8; ++mt) {
#pragma unroll
    for (int s = 0; s < 4; ++s) {
      half8 a = *(const half8*)(Wt + (size_t)(mt * 16 + np) * D + s * 32 + quad * 8);
      acc[mt] = __builtin_amdgcn_mfma_f32_16x16x32_f16(a, b[s], acc[mt], 0, 0, 0);
    }
  }

  if (node < n) {
#pragma unroll
    for (int mt = 0; mt < 8; ++mt) {
      __half2 ha = __floats2half2_rn(acc[mt][0], acc[mt][1]);
      __half2 hb = __floats2half2_rn(acc[mt][2], acc[mt][3]);
      uint2v pv;
      pv[0] = *(unsigned int*)&ha;
      pv[1] = *(unsigned int*)&hb;
      int f0 = mt * 16 + quad * 4;
      __builtin_nontemporal_store(
          pv, (uint2v*)(Y + ((size_t)(f0 >> 5) * n + node) * 32 + (f0 & 31)));
    }
  }
}

// blocks [0,gb): GEMM1 (x @ W1 -> Ya). blocks [gb,..): edge counting.
// ONE u64 atomic per edge: high32 = count, low32 = fixed-point (x65536) wsum.
__global__ __launch_bounds__(256) void k_posgemm(const float* __restrict__ x,
                                                 const __half* __restrict__ Wt,
                                                 __half* __restrict__ Y,
                                                 const int* __restrict__ ei,
                                                 const float* __restrict__ w,
                                                 unsigned long long* __restrict__ cntdeg,
                                                 int2* __restrict__ rc,
                                                 int* __restrict__ pos,
                                                 int nE, int n, int gb) {
  int b = blockIdx.x;
  if (b < gb) {
    gemm_body(b, x, Wt, Y, n);
    return;
  }
  int e = (b - gb) * blockDim.x + threadIdx.x;
  if (e >= nE) return;
  int m64 = detect64(ei);
  int r, c;
  load_edge(ei, e, nE, m64, n, r, c);
  rc[e] = make_int2(r, c);
  float wf = fminf(fmaxf(w[e], 0.0f), 65535.0f);
  unsigned long long pk =
      (1ULL << 32) | (unsigned long long)__float2uint_rn(wf * 65536.0f);
  unsigned long long old = atomicAdd(&cntdeg[(size_t)c << 3], pk);
  pos[e] = (int)(old >> 32);
}

// exclusive scan of PADDED counts (x4 -> per-node range 16B-aligned)
__global__ void k_scan1(const unsigned long long* __restrict__ cntdeg,
                        int* __restrict__ offs, int* __restrict__ bsum, int n) {
  __shared__ int s[256];
  int t = threadIdx.x;
  int i = blockIdx.x * 256 + t;
  int v = 0;
  if (i < n) {
    int cn = (int)(cntdeg[(size_t)i << 3] >> 32);
    v = (cn + 3) & ~3;
  }
  s[t] = v;
  __syncthreads();
  for (int off = 1; off < 256; off <<= 1) {
    int x = 0;
    if (t >= off) x = s[t - off];
    __syncthreads();
    if (t >= off) s[t] += x;
    __syncthreads();
  }
  if (i < n) offs[i] = s[t] - v;
  if (t == 255) bsum[blockIdx.x] = s[255];
}

// merged scan2+scan3: every block redundantly scans block sums, applies its
// offset, computes dinv.
__global__ void k_scan23(int* __restrict__ offs, const int* __restrict__ bsum,
                         const unsigned long long* __restrict__ cntdeg,
                         float* __restrict__ dinv, int n, int nb) {
  __shared__ int s[256];
  int t = threadIdx.x;
  int v = (t < nb) ? bsum[t] : 0;
  s[t] = v;
  __syncthreads();
  for (int off = 1; off < 256; off <<= 1) {
    int x = 0;
    if (t >= off) x = s[t - off];
    __syncthreads();
    if (t >= off) s[t] += x;
    __syncthreads();
  }
  int b = blockIdx.x;
  int boffb = (b == 0) ? 0 : s[b - 1];
  int i = b * 256 + t;
  if (i < n) {
    offs[i] += boffb;
    float degf =
        (float)(unsigned int)(cntdeg[(size_t)i << 3] & 0xffffffffULL) * (1.0f / 65536.0f);
    dinv[i] = rsqrtf(1.0f + degf);
  }
  if (i == 0) offs[n] = s[nb - 1];
}

// scatter packed edges (src<<16 | fp16(dinv[src]*w)) into padded CSR; zero pads.
__global__ void k_fill(const int2* __restrict__ rc, const int* __restrict__ pos,
                       const float* __restrict__ w, const int* __restrict__ offs,
                       const unsigned long long* __restrict__ cntdeg,
                       const float* __restrict__ dinv,
                       unsigned int* __restrict__ ecf2, int nE, int n) {
  int e = blockIdx.x * blockDim.x + threadIdx.x;
  if (e < nE) {
    int2 p = rc[e];
    int idx = offs[p.y] + pos[e];
    float cf = dinv[p.x] * w[e];
    ecf2[idx] = ((unsigned int)p.x << 16) |
                (unsigned int)__half_as_ushort(__float2half_rn(cf));
  }
  if (e < n) {
    int q0 = offs[e] + (int)(cntdeg[(size_t)e << 3] >> 32), q1 = offs[e + 1];
    for (int q = q0; q < q1; ++q) ecf2[q] = 0;
  }
}

// ---------------- aggregation: chunked, XCD-pinned, pipelined ---------------
// chunk = blockIdx & 3 -> round-robin block->XCD pins chunk class c to XCDs
// {c, c+4}: per-XCD gather working set = N*64B = 3.2MB < 4MB L2, so each Y
// row-slice is fetched from fabric once and its ~12 reuses hit L2.
// Block = 64 nodes x 4 lanes/node (j = t&3, 16B each -> full 64B row/edge).
// Each lane owns ALL of its node's edges in batches of 4, with an explicit
// 2-deep software pipeline (batch i+1's gathers issued before batch i is
// consumed; in-order vmcnt allows waiting on older loads while newer fly).
__device__ __forceinline__ void fmacc8(float* acc, float c, const H8& y) {
  const _Float16* hp = (const _Float16*)&y;
#pragma unroll
  for (int i = 0; i < 8; ++i) acc[i] = fmaf(c, (float)hp[i], acc[i]);  // v_fma_mix_f32
}

__device__ __forceinline__ float cdecode(unsigned int u) {
  return __half2float(__ushort_as_half((unsigned short)(u & 0xffffu)));
}

__device__ __forceinline__ void gather4(H8* y, uint4v u, const __half* __restrict__ Yc,
                                        int j) {
#pragma unroll
  for (int i = 0; i < 4; ++i)
    y[i] = *(const H8*)(Yc + (size_t)(u[i] >> 16) * 32 + j * 8);
}

__device__ __forceinline__ void accum4(float* acc, uint4v u, const H8* y) {
#pragma unroll
  for (int i = 0; i < 4; ++i) fmacc8(acc, cdecode(u[i]), y[i]);
}

template <int ACT, int PRELU, typename OutT>
__global__ __launch_bounds__(256) void k_agg(const __half* __restrict__ Yin,
                                             const int* __restrict__ offs,
                                             const unsigned int* __restrict__ ecf2,
                                             const float* __restrict__ dinv,
                                             const float* __restrict__ bias,
                                             const float* __restrict__ pw,
                                             OutT* __restrict__ OUT, int n) {
  __shared__ unsigned int sc[CAPS];
  __shared__ int soff[65];
  const int chunk = blockIdx.x & 3;
  const int t = threadIdx.x;
  const int node0 = (blockIdx.x >> 2) * 64;
  const int nl = t >> 2;          // node lane-group 0..63
  const int node = node0 + nl;
  const int j = t & 3;            // 16B piece of the 64B chunk row

  // stage this block's contiguous coef segment into LDS (coalesced, nt)
  const int seg_lo = offs[node0];
  const int seg_hi = offs[min(node0 + 64, n)];
  const int segN = min(seg_hi - seg_lo, CAPS);
  for (int i = t * 4; i < segN; i += 1024)
    *(uint4v*)&sc[i] =
        __builtin_nontemporal_load((const uint4v*)(ecf2 + seg_lo + i));
  if (t < 65) soff[t] = offs[min(node0 + t, n)];
  __syncthreads();

  const __half* Yc = Yin + (size_t)chunk * n * 32;
  const int ncl = min(node, n - 1);
  float dc = dinv[ncl];
  float acc[8] = {0.f, 0.f, 0.f, 0.f, 0.f, 0.f, 0.f, 0.f};

  // self term: issue first, consume last
  H8 ys = *(const H8*)(Yc + (size_t)ncl * 32 + j * 8);

  int lo = soff[nl], hi = soff[nl + 1];   // padded x4, 16B aligned
  if (lo < hi) {
    int k = lo - seg_lo;
    uint4v uc = (k + 4 <= CAPS) ? *(const uint4v*)&sc[k]
                                : *(const uint4v*)(ecf2 + lo);
    H8 yc[4];
    gather4(yc, uc, Yc, j);
    for (int b = lo + 4; b < hi; b += 4) {
      int k2 = b - seg_lo;
      uint4v un = (k2 + 4 <= CAPS) ? *(const uint4v*)&sc[k2]
                                   : *(const uint4v*)(ecf2 + b);
      H8 yn[4];
      gather4(yn, un, Yc, j);     // issue next batch before consuming current
      accum4(acc, uc, yc);
      uc = un;
#pragma unroll
      for (int q = 0; q < 4; ++q) yc[q] = yn[q];
    }
    accum4(acc, uc, yc);
  }
  fmacc8(acc, dc, ys);

  if (node < n) {
    floatx4 ba = *(const floatx4*)(bias + chunk * 32 + j * 8);
    floatx4 bb = *(const floatx4*)(bias + chunk * 32 + j * 8 + 4);
    float o[8];
#pragma unroll
    for (int i = 0; i < 8; ++i)
      o[i] = act_f<ACT>(dc * acc[i] + (i < 4 ? ba[i] : bb[i - 4]));
    if (PRELU) {
      float wv = *pw;
#pragma unroll
      for (int i = 0; i < 8; ++i) o[i] = o[i] >= 0.f ? o[i] : wv * o[i];
    }
    if constexpr (sizeof(OutT) == 4) {
      floatx4 v0 = {o[0], o[1], o[2], o[3]};
      floatx4 v1 = {o[4], o[5], o[6], o[7]};
      float* op = (float*)OUT + (size_t)node * D + chunk * 32 + j * 8;
      __builtin_nontemporal_store(v0, (floatx4*)op);
      __builtin_nontemporal_store(v1, (floatx4*)(op + 4));
    } else {
      H8 hw;
#pragma unroll
      for (int i = 0; i < 4; ++i) hw.h[i] = __floats2half2_rn(o[2 * i], o[2 * i + 1]);
      __builtin_nontemporal_store(
          *(uint4v*)&hw,
          (uint4v*)((__half*)OUT + ((size_t)chunk * n + node) * 32 + j * 8));
    }
  }
}

// ---------------- launch ----------------
extern "C" void kernel_launch(void* const* d_in, const int* in_sizes, int n_in,
                              void* d_out, int out_size, void* d_ws, size_t ws_size,
                              hipStream_t stream) {
  const float* x  = (const float*)d_in[0];
  const int*   ei = (const int*)d_in[1];
  const float* w  = (const float*)d_in[2];
  const float* W1 = (const float*)d_in[3];
  const float* b1 = (const float*)d_in[4];
  const float* W2 = (const float*)d_in[5];
  const float* b2 = (const float*)d_in[6];
  const float* W3 = (const float*)d_in[7];
  const float* b3 = (const float*)d_in[8];
  const float* pw = (const float*)d_in[9];
  const int N = in_sizes[0] / D;
  const int E = in_sizes[2];
  float* out = (float*)d_out;

  char* wsb = (char*)d_ws;
  size_t off = 0;
  auto alloc = [&](size_t bytes) {
    void* p = wsb + off;
    off = (off + bytes + 255) & ~(size_t)255;
    return p;
  };
  float*              dinv   = (float*)alloc((size_t)N * 4);
  unsigned long long* cntdeg = (unsigned long long*)alloc((size_t)N * 64);
  int*                offs   = (int*)alloc((size_t)(N + 1) * 4);
  int*                bsum   = (int*)alloc(256 * 4);
  unsigned int*       ecf2   = (unsigned int*)alloc(((size_t)E + 3 * (size_t)N + 64) * 4);
  __half*             Wt     = (__half*)alloc((size_t)3 * D * D * 2);
  __half*             Ya     = (__half*)alloc((size_t)N * D * 2);
  __half*             Yb     = (__half*)alloc((size_t)N * D * 2);
  __half*             h      = (__half*)alloc((size_t)N * D * 2);
  int2*               rc     = (int2*)alloc((size_t)E * 8);
  int*                pos    = (int*)alloc((size_t)E * 4);

  const int nbN = (N + 255) / 256;
  const int eb  = (E + 255) / 256;
  const int fb  = ((E > N ? E : N) + 255) / 256;
  const int n8  = N * 8;
  const int zb  = (n8 + 255) / 256;
  const int gb  = (N + 63) / 64;
  const int ab  = 4 * ((N + 63) / 64);

  hipLaunchKernelGGL(k_setup,   dim3(24 + zb), dim3(256), 0, stream, W1, W2, W3, Wt, cntdeg, n8);
  hipLaunchKernelGGL(k_posgemm, dim3(gb + eb), dim3(256), 0, stream, x, Wt, Ya, ei, w, cntdeg,
                     rc, pos, E, N, gb);
  hipLaunchKernelGGL(k_scan1,   dim3(nbN), dim3(256), 0, stream, cntdeg, offs, bsum, N);
  hipLaunchKernelGGL(k_scan23,  dim3(nbN), dim3(256), 0, stream, offs, bsum, cntdeg, dinv, N, nbN);
  hipLaunchKernelGGL(k_fill,    dim3(fb),  dim3(256), 0, stream, rc, pos, w, offs, cntdeg, dinv, ecf2, E, N);

  // layer 1 agg (+ELU) -> h ; gemm2 ; layer 2 agg (+GELU) -> h ; gemm3 ; layer 3 agg (+PReLU) -> out
  hipLaunchKernelGGL((k_agg<1, 0, __half>), dim3(ab), dim3(256), 0, stream, Ya, offs, ecf2, dinv, b1, pw, h, N);
  hipLaunchKernelGGL(k_gemmh,               dim3(gb), dim3(256), 0, stream, h, Wt + D * D,     Yb, N);
  hipLaunchKernelGGL((k_agg<2, 0, __half>), dim3(ab), dim3(256), 0, stream, Yb, offs, ecf2, dinv, b2, pw, h, N);
  hipLaunchKernelGGL(k_gemmh,               dim3(gb), dim3(256), 0, stream, h, Wt + 2 * D * D, Ya, N);
  hipLaunchKernelGGL((k_agg<0, 1, float>),  dim3(ab), dim3(256), 0, stream, Ya, offs, ecf2, dinv, b3, pw, out, N);
}

// Round 6
// 302.278 us; speedup vs baseline: 1.4021x; 1.4021x over previous
//
#include <hip/hip_runtime.h>
#include <hip/hip_fp16.h>
#include <math.h>

constexpr int D = 128;
constexpr int CAPF = 512;   // LDS coef slots per 16-node block (2KB)

struct __align__(16) H8 { __half2 h[4]; };

typedef _Float16     half8   __attribute__((ext_vector_type(8)));
typedef float        floatx4 __attribute__((ext_vector_type(4)));
typedef unsigned int uint4v  __attribute__((ext_vector_type(4)));
typedef unsigned int uint2v  __attribute__((ext_vector_type(2)));

// ---------------- preprocessing ----------------

__device__ __forceinline__ int detect64(const int* __restrict__ ei) {
  int z = 0;
#pragma unroll
  for (int i = 0; i < 8; ++i) z |= ei[2 * i + 1];
  return (z == 0) ? 1 : 0;
}

__device__ __forceinline__ void load_edge(const int* __restrict__ ei, int e, int nE,
                                          int m64, int n, int& r, int& c) {
  if (m64) { r = ei[2 * (size_t)e]; c = ei[2 * ((size_t)nE + e)]; }
  else     { r = ei[(size_t)e];     c = ei[(size_t)nE + e]; }
  r = min(max(r, 0), n - 1);
  c = min(max(c, 0), n - 1);
}

// cntdeg SPREAD: node i at cntdeg[i<<3] (one 64B line per node).
// blocks 0..23: transpose W1/W2/W3 -> Wt fp16 [n][k]; blocks 24..: zero cntdeg.
__global__ void k_setup(const float* __restrict__ W1, const float* __restrict__ W2,
                        const float* __restrict__ W3, __half* __restrict__ Wt,
                        unsigned long long* __restrict__ cntdeg, int n8) {
  int b = blockIdx.x;
  if (b < 24) {
    int m = b >> 3, s = b & 7;
    const float* W = m == 0 ? W1 : (m == 1 ? W2 : W3);
    __half* o = Wt + (size_t)m * D * D;
    int t = threadIdx.x;
    int nn = t & 127;
    int kh = t >> 7;
    int k0 = s * 16 + kh * 8;
    H8 hv;
#pragma unroll
    for (int jj = 0; jj < 4; ++jj) {
      float f0 = W[(size_t)(k0 + 2 * jj)     * D + nn];
      float f1 = W[(size_t)(k0 + 2 * jj + 1) * D + nn];
      hv.h[jj] = __floats2half2_rn(f0, f1);
    }
    *(H8*)(o + (size_t)nn * D + k0) = hv;
  } else {
    int i = (b - 24) * 256 + threadIdx.x;
    if (i < n8) cntdeg[i] = 0ULL;
  }
}

// ---------------- activations ----------------
template <int ACT>
__device__ __forceinline__ float act_f(float x) {
  if (ACT == 1) return x > 0.f ? x : expm1f(x);
  if (ACT == 2) return 0.5f * x * (1.0f + erff(x * 0.70710678118654752440f));
  return x;
}

// ---------------- MFMA GEMM body (fp32 A): Y = half(A @ W) ------------------
__device__ __forceinline__ void gemm_body(int bid, const float* __restrict__ A,
                                          const __half* __restrict__ Wt,
                                          __half* __restrict__ Y, int n) {
  const int wave = threadIdx.x >> 6;
  const int lane = threadIdx.x & 63;
  const int np = lane & 15;
  const int quad = lane >> 4;
  const int node = bid * 64 + wave * 16 + np;
  const int nc = min(node, n - 1);

  half8 b[4];
#pragma unroll
  for (int s = 0; s < 4; ++s) {
    const float* ap = A + (size_t)nc * D + s * 32 + quad * 8;
    floatx4 v0 = __builtin_nontemporal_load((const floatx4*)ap);
    floatx4 v1 = __builtin_nontemporal_load((const floatx4*)(ap + 4));
#pragma unroll
    for (int t = 0; t < 4; ++t) {
      b[s][t]     = (_Float16)v0[t];
      b[s][t + 4] = (_Float16)v1[t];
    }
  }

  floatx4 acc[8];
#pragma unroll
  for (int mt = 0; mt < 8; ++mt) acc[mt] = (floatx4){0.f, 0.f, 0.f, 0.f};

#pragma unroll
  for (int mt = 0; mt < 8; ++mt) {
#pragma unroll
    for (int s = 0; s < 4; ++s) {
      half8 a = *(const half8*)(Wt + (size_t)(mt * 16 + np) * D + s * 32 + quad * 8);
      acc[mt] = __builtin_amdgcn_mfma_f32_16x16x32_f16(a, b[s], acc[mt], 0, 0, 0);
    }
  }

  if (node < n) {
#pragma unroll
    for (int mt = 0; mt < 8; ++mt) {
      __half2 ha = __floats2half2_rn(acc[mt][0], acc[mt][1]);
      __half2 hb = __floats2half2_rn(acc[mt][2], acc[mt][3]);
      uint2v pv;
      pv[0] = *(unsigned int*)&ha;
      pv[1] = *(unsigned int*)&hb;
      int f0 = mt * 16 + quad * 4;
      __builtin_nontemporal_store(
          pv, (uint2v*)(Y + ((size_t)(f0 >> 5) * n + node) * 32 + (f0 & 31)));
    }
  }
}

// blocks [0,gb): GEMM1 (x @ W1 -> Ya). blocks [gb,..): edge counting.
// ONE u64 atomic per edge: high32 = count, low32 = fixed-point (x65536) wsum.
__global__ __launch_bounds__(256) void k_posgemm(const float* __restrict__ x,
                                                 const __half* __restrict__ Wt,
                                                 __half* __restrict__ Y,
                                                 const int* __restrict__ ei,
                                                 const float* __restrict__ w,
                                                 unsigned long long* __restrict__ cntdeg,
                                                 int2* __restrict__ rc,
                                                 int* __restrict__ pos,
                                                 int nE, int n, int gb) {
  int b = blockIdx.x;
  if (b < gb) {
    gemm_body(b, x, Wt, Y, n);
    return;
  }
  int e = (b - gb) * blockDim.x + threadIdx.x;
  if (e >= nE) return;
  int m64 = detect64(ei);
  int r, c;
  load_edge(ei, e, nE, m64, n, r, c);
  rc[e] = make_int2(r, c);
  float wf = fminf(fmaxf(w[e], 0.0f), 65535.0f);
  unsigned long long pk =
      (1ULL << 32) | (unsigned long long)__float2uint_rn(wf * 65536.0f);
  unsigned long long old = atomicAdd(&cntdeg[(size_t)c << 3], pk);
  pos[e] = (int)(old >> 32);
}

// exclusive scan of PADDED counts (x4 -> per-node range 16B-aligned)
__global__ void k_scan1(const unsigned long long* __restrict__ cntdeg,
                        int* __restrict__ offs, int* __restrict__ bsum, int n) {
  __shared__ int s[256];
  int t = threadIdx.x;
  int i = blockIdx.x * 256 + t;
  int v = 0;
  if (i < n) {
    int cn = (int)(cntdeg[(size_t)i << 3] >> 32);
    v = (cn + 3) & ~3;
  }
  s[t] = v;
  __syncthreads();
  for (int off = 1; off < 256; off <<= 1) {
    int x = 0;
    if (t >= off) x = s[t - off];
    __syncthreads();
    if (t >= off) s[t] += x;
    __syncthreads();
  }
  if (i < n) offs[i] = s[t] - v;
  if (t == 255) bsum[blockIdx.x] = s[255];
}

// merged scan2+scan3: every block redundantly scans block sums, applies its
// offset, computes dinv.
__global__ void k_scan23(int* __restrict__ offs, const int* __restrict__ bsum,
                         const unsigned long long* __restrict__ cntdeg,
                         float* __restrict__ dinv, int n, int nb) {
  __shared__ int s[256];
  int t = threadIdx.x;
  int v = (t < nb) ? bsum[t] : 0;
  s[t] = v;
  __syncthreads();
  for (int off = 1; off < 256; off <<= 1) {
    int x = 0;
    if (t >= off) x = s[t - off];
    __syncthreads();
    if (t >= off) s[t] += x;
    __syncthreads();
  }
  int b = blockIdx.x;
  int boffb = (b == 0) ? 0 : s[b - 1];
  int i = b * 256 + t;
  if (i < n) {
    offs[i] += boffb;
    float degf =
        (float)(unsigned int)(cntdeg[(size_t)i << 3] & 0xffffffffULL) * (1.0f / 65536.0f);
    dinv[i] = rsqrtf(1.0f + degf);
  }
  if (i == 0) offs[n] = s[nb - 1];
}

// scatter packed edges (src<<16 | fp16(dinv[src]*w)) into padded CSR; zero pads.
__global__ void k_fill(const int2* __restrict__ rc, const int* __restrict__ pos,
                       const float* __restrict__ w, const int* __restrict__ offs,
                       const unsigned long long* __restrict__ cntdeg,
                       const float* __restrict__ dinv,
                       unsigned int* __restrict__ ecf2, int nE, int n) {
  int e = blockIdx.x * blockDim.x + threadIdx.x;
  if (e < nE) {
    int2 p = rc[e];
    int idx = offs[p.y] + pos[e];
    float cf = dinv[p.x] * w[e];
    ecf2[idx] = ((unsigned int)p.x << 16) |
                (unsigned int)__half_as_ushort(__float2half_rn(cf));
  }
  if (e < n) {
    int q0 = offs[e] + (int)(cntdeg[(size_t)e << 3] >> 32), q1 = offs[e + 1];
    for (int q = q0; q < q1; ++q) ecf2[q] = 0;
  }
}

// ---------------- fused aggregate(+bias+act) -> MFMA gemm -------------------
// Block = 16 nodes x 16 lanes/node (lane: chunk=(t&15)>>2, j=t&3).
// Per edge the 16 lanes read the node's FULL 256B Y row (4 lines).
// Inner loop = depth-3 register ring: 3 batches x 4 edges (12 gathers) in
// flight per lane at steady state; consuming batch i waits vmcnt(8) while 8
// newer loads fly, then slot i immediately reissues at b+12.
__device__ __forceinline__ void fmacc8(float* acc, float c, const H8& y) {
  const _Float16* hp = (const _Float16*)&y;
#pragma unroll
  for (int i = 0; i < 8; ++i) acc[i] = fmaf(c, (float)hp[i], acc[i]);  // v_fma_mix_f32
}

__device__ __forceinline__ float cdecode(unsigned int u) {
  return __half2float(__ushort_as_half((unsigned short)(u & 0xffffu)));
}

__device__ __forceinline__ void gather4(H8* y, uint4v u, const __half* __restrict__ Yc,
                                        int j) {
#pragma unroll
  for (int i = 0; i < 4; ++i)
    y[i] = *(const H8*)(Yc + (size_t)(u[i] >> 16) * 32 + j * 8);
}

__device__ __forceinline__ void accum4(float* acc, uint4v u, const H8* y) {
#pragma unroll
  for (int i = 0; i < 4; ++i) fmacc8(acc, cdecode(u[i]), y[i]);
}

#define LDC(p) (((p) - seg_lo + 4 <= CAPF) ? *(const uint4v*)&sc[(p) - seg_lo] \
                                           : *(const uint4v*)(ecf2 + (p)))

// agg phase shared by k_aggemm / k_aggout. Leaves acc (pre-dinv, pre-bias).
#define AGG_PHASE()                                                              \
  const int nl = t >> 4;                                                         \
  const int node = node0 + nl;                                                   \
  const int cj = t & 15;                                                         \
  const int chunk = cj >> 2, j = cj & 3;                                         \
  const __half* Yc = Yin + (size_t)chunk * n * 32;                               \
  const int ncl = min(node, n - 1);                                              \
  float dc = dinv[ncl];                                                          \
  float acc[8] = {0.f, 0.f, 0.f, 0.f, 0.f, 0.f, 0.f, 0.f};                       \
  H8 ys = *(const H8*)(Yc + (size_t)ncl * 32 + j * 8);                           \
  {                                                                              \
    int lo = soff[nl], hi = soff[nl + 1];                                        \
    if (lo < hi) {                                                               \
      uint4v u0, u1, u2;                                                         \
      H8 y0[4], y1[4], y2[4];                                                    \
      u0 = LDC(lo);                                                              \
      gather4(y0, u0, Yc, j);                                                    \
      if (lo + 4 < hi) { u1 = LDC(lo + 4); gather4(y1, u1, Yc, j); }             \
      if (lo + 8 < hi) { u2 = LDC(lo + 8); gather4(y2, u2, Yc, j); }             \
      int b = lo;                                                                \
      while (true) {                                                             \
        accum4(acc, u0, y0);                                                     \
        if (b + 12 < hi) { u0 = LDC(b + 12); gather4(y0, u0, Yc, j); }           \
        b += 4; if (b >= hi) break;                                              \
        accum4(acc, u1, y1);                                                     \
        if (b + 12 < hi) { u1 = LDC(b + 12); gather4(y1, u1, Yc, j); }           \
        b += 4; if (b >= hi) break;                                              \
        accum4(acc, u2, y2);                                                     \
        if (b + 12 < hi) { u2 = LDC(b + 12); gather4(y2, u2, Yc, j); }           \
        b += 4; if (b >= hi) break;                                              \
      }                                                                          \
    }                                                                            \
    fmacc8(acc, dc, ys);                                                         \
  }

#define STAGE_COEFS()                                                            \
  const int t = threadIdx.x;                                                     \
  const int node0 = blockIdx.x * 16;                                             \
  if (node0 >= n) return;                                                        \
  const int seg_lo = offs[node0];                                                \
  const int seg_hi = offs[min(node0 + 16, n)];                                   \
  const int segN = min(seg_hi - seg_lo, CAPF);                                   \
  for (int i = t * 4; i < segN; i += 1024)                                       \
    *(uint4v*)&sc[i] =                                                           \
        __builtin_nontemporal_load((const uint4v*)(ecf2 + seg_lo + i));          \
  if (t < 17) soff[t] = offs[min(node0 + t, n)];                                 \
  __syncthreads();

template <int ACT>
__global__ __launch_bounds__(256, 4) void k_aggemm(
    const __half* __restrict__ Yin, const int* __restrict__ offs,
    const unsigned int* __restrict__ ecf2, const float* __restrict__ dinv,
    const float* __restrict__ bias, const __half* __restrict__ Wt,
    __half* __restrict__ Yout, int n) {
  __shared__ unsigned int sc[CAPF];
  __shared__ __half ht[16 * 136];
  __shared__ int soff[17];
  STAGE_COEFS();
  {
    AGG_PHASE();
    floatx4 ba = *(const floatx4*)(bias + chunk * 32 + j * 8);
    floatx4 bb = *(const floatx4*)(bias + chunk * 32 + j * 8 + 4);
    float o[8];
#pragma unroll
    for (int i = 0; i < 8; ++i)
      o[i] = act_f<ACT>(dc * acc[i] + (i < 4 ? ba[i] : bb[i - 4]));
    H8 hw;
#pragma unroll
    for (int i = 0; i < 4; ++i) hw.h[i] = __floats2half2_rn(o[2 * i], o[2 * i + 1]);
    if (node < n) *(H8*)&ht[nl * 136 + chunk * 32 + j * 8] = hw;
  }
  __syncthreads();

  // gemm phase: wave w -> out-feature tiles mt = 2w, 2w+1
  const int wave = t >> 6, lane = t & 63, np = lane & 15, quad = lane >> 4;
  half8 bfr[4];
#pragma unroll
  for (int s = 0; s < 4; ++s)
    bfr[s] = *(const half8*)&ht[np * 136 + s * 32 + quad * 8];
  floatx4 ga0 = (floatx4){0.f, 0.f, 0.f, 0.f};
  floatx4 ga1 = (floatx4){0.f, 0.f, 0.f, 0.f};
#pragma unroll
  for (int s = 0; s < 4; ++s) {
    half8 a0 = *(const half8*)(Wt + (size_t)((wave * 2) * 16 + np) * D + s * 32 + quad * 8);
    ga0 = __builtin_amdgcn_mfma_f32_16x16x32_f16(a0, bfr[s], ga0, 0, 0, 0);
    half8 a1 = *(const half8*)(Wt + (size_t)((wave * 2 + 1) * 16 + np) * D + s * 32 + quad * 8);
    ga1 = __builtin_amdgcn_mfma_f32_16x16x32_f16(a1, bfr[s], ga1, 0, 0, 0);
  }
  const int gnode = node0 + np;
  if (gnode < n) {
    floatx4 g[2] = {ga0, ga1};
#pragma unroll
    for (int mi = 0; mi < 2; ++mi) {
      int mt = wave * 2 + mi;
      __half2 ha = __floats2half2_rn(g[mi][0], g[mi][1]);
      __half2 hb = __floats2half2_rn(g[mi][2], g[mi][3]);
      uint2v pv;
      pv[0] = *(unsigned int*)&ha;
      pv[1] = *(unsigned int*)&hb;
      int f0 = mt * 16 + quad * 4;
      __builtin_nontemporal_store(
          pv, (uint2v*)(Yout + ((size_t)(f0 >> 5) * n + gnode) * 32 + (f0 & 31)));
    }
  }
}

__global__ __launch_bounds__(256, 4) void k_aggout(
    const __half* __restrict__ Yin, const int* __restrict__ offs,
    const unsigned int* __restrict__ ecf2, const float* __restrict__ dinv,
    const float* __restrict__ bias, const float* __restrict__ pw,
    float* __restrict__ out, int n) {
  __shared__ unsigned int sc[CAPF];
  __shared__ int soff[17];
  STAGE_COEFS();
  AGG_PHASE();
  if (node < n) {
    floatx4 ba = *(const floatx4*)(bias + chunk * 32 + j * 8);
    floatx4 bb = *(const floatx4*)(bias + chunk * 32 + j * 8 + 4);
    float wv = *pw;
    floatx4 v0, v1;
#pragma unroll
    for (int i = 0; i < 4; ++i) {
      float o = dc * acc[i] + ba[i];
      v0[i] = o >= 0.f ? o : wv * o;
    }
#pragma unroll
    for (int i = 0; i < 4; ++i) {
      float o = dc * acc[4 + i] + bb[i];
      v1[i] = o >= 0.f ? o : wv * o;
    }
    float* op = out + (size_t)node * D + chunk * 32 + j * 8;
    __builtin_nontemporal_store(v0, (floatx4*)op);
    __builtin_nontemporal_store(v1, (floatx4*)(op + 4));
  }
}

// ---------------- launch ----------------
extern "C" void kernel_launch(void* const* d_in, const int* in_sizes, int n_in,
                              void* d_out, int out_size, void* d_ws, size_t ws_size,
                              hipStream_t stream) {
  const float* x  = (const float*)d_in[0];
  const int*   ei = (const int*)d_in[1];
  const float* w  = (const float*)d_in[2];
  const float* W1 = (const float*)d_in[3];
  const float* b1 = (const float*)d_in[4];
  const float* W2 = (const float*)d_in[5];
  const float* b2 = (const float*)d_in[6];
  const float* W3 = (const float*)d_in[7];
  const float* b3 = (const float*)d_in[8];
  const float* pw = (const float*)d_in[9];
  const int N = in_sizes[0] / D;
  const int E = in_sizes[2];
  float* out = (float*)d_out;

  char* wsb = (char*)d_ws;
  size_t off = 0;
  auto alloc = [&](size_t bytes) {
    void* p = wsb + off;
    off = (off + bytes + 255) & ~(size_t)255;
    return p;
  };
  float*              dinv   = (float*)alloc((size_t)N * 4);
  unsigned long long* cntdeg = (unsigned long long*)alloc((size_t)N * 64);
  int*                offs   = (int*)alloc((size_t)(N + 1) * 4);
  int*                bsum   = (int*)alloc(256 * 4);
  unsigned int*       ecf2   = (unsigned int*)alloc(((size_t)E + 3 * (size_t)N + 64) * 4);
  __half*             Wt     = (__half*)alloc((size_t)3 * D * D * 2);
  __half*             Ya     = (__half*)alloc((size_t)N * D * 2);
  __half*             Yb     = (__half*)alloc((size_t)N * D * 2);
  int2*               rc     = (int2*)alloc((size_t)E * 8);
  int*                pos    = (int*)alloc((size_t)E * 4);

  const int nbN = (N + 255) / 256;
  const int eb  = (E + 255) / 256;
  const int fb  = ((E > N ? E : N) + 255) / 256;
  const int n8  = N * 8;
  const int zb  = (n8 + 255) / 256;
  const int gb  = (N + 63) / 64;
  const int abf = (N + 15) / 16;

  hipLaunchKernelGGL(k_setup,   dim3(24 + zb), dim3(256), 0, stream, W1, W2, W3, Wt, cntdeg, n8);
  hipLaunchKernelGGL(k_posgemm, dim3(gb + eb), dim3(256), 0, stream, x, Wt, Ya, ei, w, cntdeg,
                     rc, pos, E, N, gb);
  hipLaunchKernelGGL(k_scan1,   dim3(nbN), dim3(256), 0, stream, cntdeg, offs, bsum, N);
  hipLaunchKernelGGL(k_scan23,  dim3(nbN), dim3(256), 0, stream, offs, bsum, cntdeg, dinv, N, nbN);
  hipLaunchKernelGGL(k_fill,    dim3(fb),  dim3(256), 0, stream, rc, pos, w, offs, cntdeg, dinv, ecf2, E, N);

  hipLaunchKernelGGL((k_aggemm<1>), dim3(abf), dim3(256), 0, stream, Ya, offs, ecf2, dinv, b1, Wt + D * D,     Yb, N);
  hipLaunchKernelGGL((k_aggemm<2>), dim3(abf), dim3(256), 0, stream, Yb, offs, ecf2, dinv, b2, Wt + 2 * D * D, Ya, N);
  hipLaunchKernelGGL(k_aggout,      dim3(abf), dim3(256), 0, stream, Ya, offs, ecf2, dinv, b3, pw, out, N);
}

// Round 7
// 283.445 us; speedup vs baseline: 1.4953x; 1.0664x over previous
//
#include <hip/hip_runtime.h>
#include <hip/hip_fp16.h>
#include <math.h>

constexpr int D = 128;
constexpr int CAPC = 1024;   // LDS coef slots per 32-node agg block (4KB)

struct __align__(16) H8 { __half2 h[4]; };

typedef _Float16     half8   __attribute__((ext_vector_type(8)));
typedef float        floatx4 __attribute__((ext_vector_type(4)));
typedef unsigned int uint4v  __attribute__((ext_vector_type(4)));
typedef unsigned int uint2v  __attribute__((ext_vector_type(2)));

// ---------------- preprocessing ----------------

__device__ __forceinline__ int detect64(const int* __restrict__ ei) {
  int z = 0;
#pragma unroll
  for (int i = 0; i < 8; ++i) z |= ei[2 * i + 1];
  return (z == 0) ? 1 : 0;
}

__device__ __forceinline__ void load_edge(const int* __restrict__ ei, int e, int nE,
                                          int m64, int n, int& r, int& c) {
  if (m64) { r = ei[2 * (size_t)e]; c = ei[2 * ((size_t)nE + e)]; }
  else     { r = ei[(size_t)e];     c = ei[(size_t)nE + e]; }
  r = min(max(r, 0), n - 1);
  c = min(max(c, 0), n - 1);
}

// cntdeg SPREAD: node i at cntdeg[i<<3] (one 64B line per node).
// blocks 0..23: transpose W1/W2/W3 -> Wt fp16 [n][k]; blocks 24..: zero cntdeg.
__global__ void k_setup(const float* __restrict__ W1, const float* __restrict__ W2,
                        const float* __restrict__ W3, __half* __restrict__ Wt,
                        unsigned long long* __restrict__ cntdeg, int n8) {
  int b = blockIdx.x;
  if (b < 24) {
    int m = b >> 3, s = b & 7;
    const float* W = m == 0 ? W1 : (m == 1 ? W2 : W3);
    __half* o = Wt + (size_t)m * D * D;
    int t = threadIdx.x;
    int nn = t & 127;
    int kh = t >> 7;
    int k0 = s * 16 + kh * 8;
    H8 hv;
#pragma unroll
    for (int jj = 0; jj < 4; ++jj) {
      float f0 = W[(size_t)(k0 + 2 * jj)     * D + nn];
      float f1 = W[(size_t)(k0 + 2 * jj + 1) * D + nn];
      hv.h[jj] = __floats2half2_rn(f0, f1);
    }
    *(H8*)(o + (size_t)nn * D + k0) = hv;
  } else {
    int i = (b - 24) * 256 + threadIdx.x;
    if (i < n8) cntdeg[i] = 0ULL;
  }
}

// ---------------- activations ----------------
template <int ACT>
__device__ __forceinline__ float act_f(float x) {
  if (ACT == 1) return x > 0.f ? x : expm1f(x);
  if (ACT == 2) return 0.5f * x * (1.0f + erff(x * 0.70710678118654752440f));
  return x;
}

// ---------------- MFMA GEMM body (fp32 A): Y = half(A @ W) ------------------
__device__ __forceinline__ void gemm_body(int bid, const float* __restrict__ A,
                                          const __half* __restrict__ Wt,
                                          __half* __restrict__ Y, int n) {
  const int wave = threadIdx.x >> 6;
  const int lane = threadIdx.x & 63;
  const int np = lane & 15;
  const int quad = lane >> 4;
  const int node = bid * 64 + wave * 16 + np;
  const int nc = min(node, n - 1);

  half8 b[4];
#pragma unroll
  for (int s = 0; s < 4; ++s) {
    const float* ap = A + (size_t)nc * D + s * 32 + quad * 8;
    floatx4 v0 = __builtin_nontemporal_load((const floatx4*)ap);
    floatx4 v1 = __builtin_nontemporal_load((const floatx4*)(ap + 4));
#pragma unroll
    for (int t = 0; t < 4; ++t) {
      b[s][t]     = (_Float16)v0[t];
      b[s][t + 4] = (_Float16)v1[t];
    }
  }

  floatx4 acc[8];
#pragma unroll
  for (int mt = 0; mt < 8; ++mt) acc[mt] = (floatx4){0.f, 0.f, 0.f, 0.f};

#pragma unroll
  for (int mt = 0; mt < 8; ++mt) {
#pragma unroll
    for (int s = 0; s < 4; ++s) {
      half8 a = *(const half8*)(Wt + (size_t)(mt * 16 + np) * D + s * 32 + quad * 8);
      acc[mt] = __builtin_amdgcn_mfma_f32_16x16x32_f16(a, b[s], acc[mt], 0, 0, 0);
    }
  }

  if (node < n) {
#pragma unroll
    for (int mt = 0; mt < 8; ++mt) {
      __half2 ha = __floats2half2_rn(acc[mt][0], acc[mt][1]);
      __half2 hb = __floats2half2_rn(acc[mt][2], acc[mt][3]);
      uint2v pv;
      pv[0] = *(unsigned int*)&ha;
      pv[1] = *(unsigned int*)&hb;
      int f0 = mt * 16 + quad * 4;
      __builtin_nontemporal_store(
          pv, (uint2v*)(Y + ((size_t)(f0 >> 5) * n + node) * 32 + (f0 & 31)));
    }
  }
}

// half-input (chunk layout, already activated) GEMM: Y = half(A @ W)
__global__ __launch_bounds__(256) void k_gemmh(const __half* __restrict__ A,
                                               const __half* __restrict__ Wt,
                                               __half* __restrict__ Y, int n) {
  const int wave = threadIdx.x >> 6;
  const int lane = threadIdx.x & 63;
  const int np = lane & 15;
  const int quad = lane >> 4;
  const int node = blockIdx.x * 64 + wave * 16 + np;
  const int nc = min(node, n - 1);

  half8 b[4];
#pragma unroll
  for (int s = 0; s < 4; ++s)
    b[s] = __builtin_nontemporal_load(
        (const half8*)(A + ((size_t)s * n + nc) * 32 + quad * 8));

  floatx4 acc[8];
#pragma unroll
  for (int mt = 0; mt < 8; ++mt) acc[mt] = (floatx4){0.f, 0.f, 0.f, 0.f};

#pragma unroll
  for (int mt = 0; mt < 8; ++mt) {
#pragma unroll
    for (int s = 0; s < 4; ++s) {
      half8 a = *(const half8*)(Wt + (size_t)(mt * 16 + np) * D + s * 32 + quad * 8);
      acc[mt] = __builtin_amdgcn_mfma_f32_16x16x32_f16(a, b[s], acc[mt], 0, 0, 0);
    }
  }

  if (node < n) {
#pragma unroll
    for (int mt = 0; mt < 8; ++mt) {
      __half2 ha = __floats2half2_rn(acc[mt][0], acc[mt][1]);
      __half2 hb = __floats2half2_rn(acc[mt][2], acc[mt][3]);
      uint2v pv;
      pv[0] = *(unsigned int*)&ha;
      pv[1] = *(unsigned int*)&hb;
      int f0 = mt * 16 + quad * 4;
      __builtin_nontemporal_store(
          pv, (uint2v*)(Y + ((size_t)(f0 >> 5) * n + node) * 32 + (f0 & 31)));
    }
  }
}

// blocks [0,gb): GEMM1 (x @ W1 -> Ya). blocks [gb,..): edge counting.
// ONE u64 atomic per edge: high32 = count, low32 = fixed-point (x65536) wsum.
__global__ __launch_bounds__(256) void k_posgemm(const float* __restrict__ x,
                                                 const __half* __restrict__ Wt,
                                                 __half* __restrict__ Y,
                                                 const int* __restrict__ ei,
                                                 const float* __restrict__ w,
                                                 unsigned long long* __restrict__ cntdeg,
                                                 int2* __restrict__ rc,
                                                 int* __restrict__ pos,
                                                 int nE, int n, int gb) {
  int b = blockIdx.x;
  if (b < gb) {
    gemm_body(b, x, Wt, Y, n);
    return;
  }
  int e = (b - gb) * blockDim.x + threadIdx.x;
  if (e >= nE) return;
  int m64 = detect64(ei);
  int r, c;
  load_edge(ei, e, nE, m64, n, r, c);
  rc[e] = make_int2(r, c);
  float wf = fminf(fmaxf(w[e], 0.0f), 65535.0f);
  unsigned long long pk =
      (1ULL << 32) | (unsigned long long)__float2uint_rn(wf * 65536.0f);
  unsigned long long old = atomicAdd(&cntdeg[(size_t)c << 3], pk);
  pos[e] = (int)(old >> 32);
}

// exclusive scan of PADDED counts (x4 -> per-node range 16B-aligned)
__global__ void k_scan1(const unsigned long long* __restrict__ cntdeg,
                        int* __restrict__ offs, int* __restrict__ bsum, int n) {
  __shared__ int s[256];
  int t = threadIdx.x;
  int i = blockIdx.x * 256 + t;
  int v = 0;
  if (i < n) {
    int cn = (int)(cntdeg[(size_t)i << 3] >> 32);
    v = (cn + 3) & ~3;
  }
  s[t] = v;
  __syncthreads();
  for (int off = 1; off < 256; off <<= 1) {
    int x = 0;
    if (t >= off) x = s[t - off];
    __syncthreads();
    if (t >= off) s[t] += x;
    __syncthreads();
  }
  if (i < n) offs[i] = s[t] - v;
  if (t == 255) bsum[blockIdx.x] = s[255];
}

// merged scan2+scan3: every block redundantly scans block sums, applies its
// offset, computes dinv.
__global__ void k_scan23(int* __restrict__ offs, const int* __restrict__ bsum,
                         const unsigned long long* __restrict__ cntdeg,
                         float* __restrict__ dinv, int n, int nb) {
  __shared__ int s[256];
  int t = threadIdx.x;
  int v = (t < nb) ? bsum[t] : 0;
  s[t] = v;
  __syncthreads();
  for (int off = 1; off < 256; off <<= 1) {
    int x = 0;
    if (t >= off) x = s[t - off];
    __syncthreads();
    if (t >= off) s[t] += x;
    __syncthreads();
  }
  int b = blockIdx.x;
  int boffb = (b == 0) ? 0 : s[b - 1];
  int i = b * 256 + t;
  if (i < n) {
    offs[i] += boffb;
    float degf =
        (float)(unsigned int)(cntdeg[(size_t)i << 3] & 0xffffffffULL) * (1.0f / 65536.0f);
    dinv[i] = rsqrtf(1.0f + degf);
  }
  if (i == 0) offs[n] = s[nb - 1];
}

// scatter packed edges (src<<16 | fp16(dinv[src]*w)) into padded CSR; zero pads.
__global__ void k_fill(const int2* __restrict__ rc, const int* __restrict__ pos,
                       const float* __restrict__ w, const int* __restrict__ offs,
                       const unsigned long long* __restrict__ cntdeg,
                       const float* __restrict__ dinv,
                       unsigned int* __restrict__ ecf2, int nE, int n) {
  int e = blockIdx.x * blockDim.x + threadIdx.x;
  if (e < nE) {
    int2 p = rc[e];
    int idx = offs[p.y] + pos[e];
    float cf = dinv[p.x] * w[e];
    ecf2[idx] = ((unsigned int)p.x << 16) |
                (unsigned int)__half_as_ushort(__float2half_rn(cf));
  }
  if (e < n) {
    int q0 = offs[e] + (int)(cntdeg[(size_t)e << 3] >> 32), q1 = offs[e + 1];
    for (int q = q0; q < q1; ++q) ecf2[q] = 0;
  }
}

// ---------------- aggregation: chunked, XCD-pinned, copy-free ring ----------
// chunk = blockIdx & 3 -> round-robin block->XCD pins chunk class c to XCDs
// {c, c+4}: per-XCD gather working set = N*64B = 3.2MB < 4MB L2 -> gathers
// are L2 hits after the first touch (verified R5: FETCH 135 -> 19 MB).
// Block = 32 nodes x 8 lanes/node (sub = (t>>2)&1 edge half-range, j = t&3
// 16B piece). Each sub runs a copy-free 2-slot ring over batches of 4 edges:
// per node 16 edge-lines in flight (R5's fatal loop-carried register copies
// -- which forced a full vmcnt drain per batch -- are gone).
__device__ __forceinline__ void fmacc8(float* acc, float c, const H8& y) {
  const _Float16* hp = (const _Float16*)&y;
#pragma unroll
  for (int i = 0; i < 8; ++i) acc[i] = fmaf(c, (float)hp[i], acc[i]);  // v_fma_mix_f32
}

__device__ __forceinline__ float cdecode(unsigned int u) {
  return __half2float(__ushort_as_half((unsigned short)(u & 0xffffu)));
}

__device__ __forceinline__ void gather4(H8* y, uint4v u, const __half* __restrict__ Yc,
                                        int j) {
#pragma unroll
  for (int i = 0; i < 4; ++i)
    y[i] = *(const H8*)(Yc + (size_t)(u[i] >> 16) * 32 + j * 8);
}

__device__ __forceinline__ void accum4(float* acc, uint4v u, const H8* y) {
#pragma unroll
  for (int i = 0; i < 4; ++i) fmacc8(acc, cdecode(u[i]), y[i]);
}

#define LDC(p) (((p) - seg_lo + 4 <= CAPC) ? *(const uint4v*)&sc[(p) - seg_lo] \
                                           : *(const uint4v*)(ecf2 + (p)))

template <int ACT, int PRELU, typename OutT>
__global__ __launch_bounds__(256) void k_agg(const __half* __restrict__ Yin,
                                             const int* __restrict__ offs,
                                             const unsigned int* __restrict__ ecf2,
                                             const float* __restrict__ dinv,
                                             const float* __restrict__ bias,
                                             const float* __restrict__ pw,
                                             OutT* __restrict__ OUT, int n) {
  __shared__ unsigned int sc[CAPC];
  __shared__ int soff[33];
  const int chunk = blockIdx.x & 3;
  const int t = threadIdx.x;
  const int node0 = (blockIdx.x >> 2) * 32;
  const int nl = t >> 3;          // node 0..31
  const int node = node0 + nl;
  const int sub = (t >> 2) & 1;   // edge half-range
  const int j = t & 3;            // 16B piece of the 64B chunk slice

  // stage this block's contiguous coef segment into LDS (coalesced, nt)
  const int seg_lo = offs[node0];
  const int seg_hi = offs[min(node0 + 32, n)];
  const int segN = min(seg_hi - seg_lo, CAPC);
  for (int i = t * 4; i < segN; i += 1024)
    *(uint4v*)&sc[i] =
        __builtin_nontemporal_load((const uint4v*)(ecf2 + seg_lo + i));
  if (t < 33) soff[t] = offs[min(node0 + t, n)];
  __syncthreads();

  const __half* Yc = Yin + (size_t)chunk * n * 32;
  const int ncl = min(node, n - 1);
  float dc = dinv[ncl];
  float acc[8] = {0.f, 0.f, 0.f, 0.f, 0.f, 0.f, 0.f, 0.f};

  // self term (sub0 only): issue first, consume last
  H8 ys{};
  if (sub == 0) ys = *(const H8*)(Yc + (size_t)ncl * 32 + j * 8);

  int lo = soff[nl], hi = soff[nl + 1];   // padded x4, 16B aligned
  int nb4 = (hi - lo) >> 2;
  int em = lo + (((nb4 + 1) >> 1) << 2);  // sub0: [lo,em)  sub1: [em,hi)
  int b0 = sub ? em : lo;
  int be = sub ? hi : em;
  if (b0 < be) {
    uint4v u0, u1;
    H8 y0[4], y1[4];
    u0 = LDC(b0);
    gather4(y0, u0, Yc, j);
    if (b0 + 4 < be) { u1 = LDC(b0 + 4); gather4(y1, u1, Yc, j); }
    int b = b0;
    while (true) {
      accum4(acc, u0, y0);
      if (b + 8 < be) { u0 = LDC(b + 8); gather4(y0, u0, Yc, j); }
      b += 4; if (b >= be) break;
      accum4(acc, u1, y1);
      if (b + 8 < be) { u1 = LDC(b + 8); gather4(y1, u1, Yc, j); }
      b += 4; if (b >= be) break;
    }
  }
  if (sub == 0) fmacc8(acc, dc, ys);

  // combine sub pair (lanes differ in bit 2); sub0 lane then owns the full sum
#pragma unroll
  for (int i = 0; i < 8; ++i) acc[i] += __shfl_xor(acc[i], 4, 64);

  if (sub == 0 && node < n) {
    floatx4 ba = *(const floatx4*)(bias + chunk * 32 + j * 8);
    floatx4 bb = *(const floatx4*)(bias + chunk * 32 + j * 8 + 4);
    float o[8];
#pragma unroll
    for (int i = 0; i < 8; ++i)
      o[i] = act_f<ACT>(dc * acc[i] + (i < 4 ? ba[i] : bb[i - 4]));
    if (PRELU) {
      float wv = *pw;
#pragma unroll
      for (int i = 0; i < 8; ++i) o[i] = o[i] >= 0.f ? o[i] : wv * o[i];
    }
    if constexpr (sizeof(OutT) == 4) {
      floatx4 v0 = {o[0], o[1], o[2], o[3]};
      floatx4 v1 = {o[4], o[5], o[6], o[7]};
      float* op = (float*)OUT + (size_t)node * D + chunk * 32 + j * 8;
      __builtin_nontemporal_store(v0, (floatx4*)op);
      __builtin_nontemporal_store(v1, (floatx4*)(op + 4));
    } else {
      H8 hw;
#pragma unroll
      for (int i = 0; i < 4; ++i) hw.h[i] = __floats2half2_rn(o[2 * i], o[2 * i + 1]);
      __builtin_nontemporal_store(
          *(uint4v*)&hw,
          (uint4v*)((__half*)OUT + ((size_t)chunk * n + node) * 32 + j * 8));
    }
  }
}

// ---------------- launch ----------------
extern "C" void kernel_launch(void* const* d_in, const int* in_sizes, int n_in,
                              void* d_out, int out_size, void* d_ws, size_t ws_size,
                              hipStream_t stream) {
  const float* x  = (const float*)d_in[0];
  const int*   ei = (const int*)d_in[1];
  const float* w  = (const float*)d_in[2];
  const float* W1 = (const float*)d_in[3];
  const float* b1 = (const float*)d_in[4];
  const float* W2 = (const float*)d_in[5];
  const float* b2 = (const float*)d_in[6];
  const float* W3 = (const float*)d_in[7];
  const float* b3 = (const float*)d_in[8];
  const float* pw = (const float*)d_in[9];
  const int N = in_sizes[0] / D;
  const int E = in_sizes[2];
  float* out = (float*)d_out;

  char* wsb = (char*)d_ws;
  size_t off = 0;
  auto alloc = [&](size_t bytes) {
    void* p = wsb + off;
    off = (off + bytes + 255) & ~(size_t)255;
    return p;
  };
  float*              dinv   = (float*)alloc((size_t)N * 4);
  unsigned long long* cntdeg = (unsigned long long*)alloc((size_t)N * 64);
  int*                offs   = (int*)alloc((size_t)(N + 1) * 4);
  int*                bsum   = (int*)alloc(256 * 4);
  unsigned int*       ecf2   = (unsigned int*)alloc(((size_t)E + 3 * (size_t)N + 64) * 4);
  __half*             Wt     = (__half*)alloc((size_t)3 * D * D * 2);
  __half*             Ya     = (__half*)alloc((size_t)N * D * 2);
  __half*             Yb     = (__half*)alloc((size_t)N * D * 2);
  __half*             h      = (__half*)alloc((size_t)N * D * 2);
  int2*               rc     = (int2*)alloc((size_t)E * 8);
  int*                pos    = (int*)alloc((size_t)E * 4);

  const int nbN = (N + 255) / 256;
  const int eb  = (E + 255) / 256;
  const int fb  = ((E > N ? E : N) + 255) / 256;
  const int n8  = N * 8;
  const int zb  = (n8 + 255) / 256;
  const int gb  = (N + 63) / 64;
  const int ab  = 4 * ((N + 31) / 32);

  hipLaunchKernelGGL(k_setup,   dim3(24 + zb), dim3(256), 0, stream, W1, W2, W3, Wt, cntdeg, n8);
  hipLaunchKernelGGL(k_posgemm, dim3(gb + eb), dim3(256), 0, stream, x, Wt, Ya, ei, w, cntdeg,
                     rc, pos, E, N, gb);
  hipLaunchKernelGGL(k_scan1,   dim3(nbN), dim3(256), 0, stream, cntdeg, offs, bsum, N);
  hipLaunchKernelGGL(k_scan23,  dim3(nbN), dim3(256), 0, stream, offs, bsum, cntdeg, dinv, N, nbN);
  hipLaunchKernelGGL(k_fill,    dim3(fb),  dim3(256), 0, stream, rc, pos, w, offs, cntdeg, dinv, ecf2, E, N);

  hipLaunchKernelGGL((k_agg<1, 0, __half>), dim3(ab), dim3(256), 0, stream, Ya, offs, ecf2, dinv, b1, pw, h, N);
  hipLaunchKernelGGL(k_gemmh,               dim3(gb), dim3(256), 0, stream, h, Wt + D * D,     Yb, N);
  hipLaunchKernelGGL((k_agg<2, 0, __half>), dim3(ab), dim3(256), 0, stream, Yb, offs, ecf2, dinv, b2, pw, h, N);
  hipLaunchKernelGGL(k_gemmh,               dim3(gb), dim3(256), 0, stream, h, Wt + 2 * D * D, Ya, N);
  hipLaunchKernelGGL((k_agg<0, 1, float>),  dim3(ab), dim3(256), 0, stream, Ya, offs, ecf2, dinv, b3, pw, out, N);
}